// Round 10
// baseline (2101.258 us; speedup 1.0000x reference)
//
#include <hip/hip_runtime.h>

#define HDIM   512
#define BROWS  32
#define NTHR   512      // 8 waves; wave wv owns cols [64*wv, 64*wv+64) of H=512
#define LDA    520      // ushort elems per LDS row: 512 + 8 pad (breaks bank aliasing)
#define STLD   9        // float2 per stats row (8 waves + 1 pad)
#define NSTEPS 10
#define DT     0.1f
#define LNEPS  1e-5f
#define NLOG2E -1.4426950408889634f   // W_in/W_rec/bias pre-scaled: exp(-arg) == exp2(acc)

typedef __attribute__((ext_vector_type(8))) short v8s;   // 8 bf16 (4 VGPRs) MFMA operand
typedef __attribute__((ext_vector_type(4))) float v4f;   // 4 fp32 MFMA accum

static __device__ __forceinline__ ushort f2bf(float f) {
  union { float f; unsigned u; } v; v.f = f;
  unsigned r = v.u + 0x7fffu + ((v.u >> 16) & 1u);   // RNE
  return (ushort)(r >> 16);
}
static __device__ __forceinline__ float ubf2f(unsigned bits) {
  union { unsigned u; float f; } v; v.u = bits;
  return v.f;
}
// packed RNE bf16 pair: lo -> [15:0], hi -> [31:16] (bit-exact vs f2bf)
static __device__ __forceinline__ unsigned cvt_pk_bf16(float lo, float hi) {
  unsigned r;
  asm("v_cvt_pk_bf16_f32 %0, %1, %2" : "=v"(r) : "v"(lo), "v"(hi));
  return r;
}
static __device__ __forceinline__ float fexp2(float x) {
#if __has_builtin(__builtin_amdgcn_exp2f)
  return __builtin_amdgcn_exp2f(x);
#else
  float r; asm("v_exp_f32 %0, %1" : "=v"(r) : "v"(x)); return r;
#endif
}
// sum over the 16 lanes of each DPP row (lanes sharing q); result in every lane.
static __device__ __forceinline__ float rowsum16(float x) {
  union { float f; int i; } u, v;
  u.f = x;
  v.i = __builtin_amdgcn_update_dpp(0, u.i, 0x121, 0xf, 0xf, false); u.f += v.f; // ror:1
  v.i = __builtin_amdgcn_update_dpp(0, u.i, 0x122, 0xf, 0xf, false); u.f += v.f; // ror:2
  v.i = __builtin_amdgcn_update_dpp(0, u.i, 0x124, 0xf, 0xf, false); u.f += v.f; // ror:4
  v.i = __builtin_amdgcn_update_dpp(0, u.i, 0x128, 0xf, 0xf, false); u.f += v.f; // ror:8
  return u.f;
}

// ---------------------------------------------------------------------------
// Pack a weight matrix into MFMA B-fragment order, bf16 (x scale):
//   B[k][n] with k = kc*32 + (lane>>4)*8 + j, n = ctg*16 + (lane&15)
//   dst frag index f = (kc*NT + ctg)*64 + lane, 8 bf16 each (16B, coalesced).
// trans==0: B[k][n] = src[k*N + n]          (W_in: x @ W)
// trans==1: B[k][n] = src[n*K + k] (*mask)  (W_rec^T masked, out_W^T)
// ---------------------------------------------------------------------------
__global__ void pack_w(const float* __restrict__ src, const float* __restrict__ msk,
                       ushort* __restrict__ dst, int K, int N, int trans, float scale) {
  int nt = N >> 4;
  int tot = (K >> 5) * nt * 64;
  int f = blockIdx.x * blockDim.x + threadIdx.x;
  if (f >= tot) return;
  int flane = f & 63;
  int rest = f >> 6;
  int ctg = rest % nt;
  int kc = rest / nt;
  int n = ctg * 16 + (flane & 15);
  int kb = kc * 32 + ((flane >> 4) & 3) * 8;
  ushort v[8];
#pragma unroll
  for (int j = 0; j < 8; ++j) {
    int k = kb + j;
    float s;
    if (trans) {
      s = src[(size_t)n * K + k];
      if (msk) s *= msk[(size_t)n * K + k];
    } else {
      s = src[(size_t)k * N + n];
    }
    v[j] = f2bf(s * scale);
  }
  uint4 u;
  u.x = (unsigned)v[0] | ((unsigned)v[1] << 16);
  u.y = (unsigned)v[2] | ((unsigned)v[3] << 16);
  u.z = (unsigned)v[4] | ((unsigned)v[5] << 16);
  u.w = (unsigned)v[6] | ((unsigned)v[7] << 16);
  *(uint4*)(dst + (size_t)f * 8) = u;
}

// ---------------------------------------------------------------------------
// GEMM: acc[rt][ct] = (ZI ? 0 : init[rt][ct]) + hb(16*RT x 32*KC) @ W(32*KC x 16*NT)
// (VERBATIM round-4 codegen — proven spill-free; used for W_in / out_W)
// ---------------------------------------------------------------------------
template <int KC, int NT, int NCT, int RT, bool ZI>
static __device__ __forceinline__ void gemm_tiles(const ushort* hb, const ushort* __restrict__ w,
                                                  int wv, int lane, v4f acc[RT][NCT],
                                                  const v4f init[RT][NCT]) {
  const int q = lane >> 4, n = lane & 15;
#pragma unroll
  for (int rt = 0; rt < RT; ++rt)
#pragma unroll
    for (int ct = 0; ct < NCT; ++ct)
      acc[rt][ct] = ZI ? (v4f){0.f, 0.f, 0.f, 0.f} : init[rt][ct];
#pragma unroll
  for (int kc = 0; kc < KC; ++kc) {
    v8s a[RT];
#pragma unroll
    for (int rt = 0; rt < RT; ++rt)
      a[rt] = *(const v8s*)(hb + (rt * 16 + n) * LDA + kc * 32 + q * 8);
#pragma unroll
    for (int ct = 0; ct < NCT; ++ct) {
      const int ctg = wv * NCT + ct;
      v8s b = *(const v8s*)(w + ((size_t)(kc * NT + ctg) * 64 + lane) * 8);
#pragma unroll
      for (int rt = 0; rt < RT; ++rt)
        acc[rt][ct] = __builtin_amdgcn_mfma_f32_16x16x32_bf16(a[rt], b, acc[rt][ct], 0, 0, 0);
    }
  }
}

// ---------------------------------------------------------------------------
// Rec-GEMM variant: kc=0's four B-fragments are RESIDENT in registers
// (loop-invariant across the 10 ODE steps — loaded once per layer). The
// first 16 MFMAs after the barrier need no VMEM, covering the post-barrier
// L2 latency ramp while kc>=1 loads issue. Scalar v8s params (not arrays):
// round-6 lesson — array params alloca to scratch even when forceinlined.
// ---------------------------------------------------------------------------
template <int KC, int NT, int NCT, int RT>
static __device__ __forceinline__ void gemm_tiles_pf(const ushort* hb, const ushort* __restrict__ w,
                                                     int wv, int lane, v4f acc[RT][NCT],
                                                     const v4f init[RT][NCT],
                                                     v8s pb0, v8s pb1, v8s pb2, v8s pb3) {
  const int q = lane >> 4, n = lane & 15;
#pragma unroll
  for (int rt = 0; rt < RT; ++rt)
#pragma unroll
    for (int ct = 0; ct < NCT; ++ct)
      acc[rt][ct] = init[rt][ct];
#pragma unroll
  for (int kc = 0; kc < KC; ++kc) {
    v8s a[RT];
#pragma unroll
    for (int rt = 0; rt < RT; ++rt)
      a[rt] = *(const v8s*)(hb + (rt * 16 + n) * LDA + kc * 32 + q * 8);
#pragma unroll
    for (int ct = 0; ct < NCT; ++ct) {
      v8s b;
      if (kc == 0) {
        b = (ct == 0) ? pb0 : (ct == 1) ? pb1 : (ct == 2) ? pb2 : pb3;
      } else {
        const int ctg = wv * NCT + ct;
        b = *(const v8s*)(w + ((size_t)(kc * NT + ctg) * 64 + lane) * 8);
      }
#pragma unroll
      for (int rt = 0; rt < RT; ++rt)
        acc[rt][ct] = __builtin_amdgcn_mfma_f32_16x16x32_bf16(a[rt], b, acc[rt][ct], 0, 0, 0);
    }
  }
}

struct LayerP {
  const ushort* win;
  const ushort* wrec;
  const float* bias;
  const float* tau;
  const float* Aamp;
  const float* g;
  const float* b;
};
struct KP {
  const float* x;
  LayerP L[3];
  const ushort* wout;
  const float* outb;
  float* out;
};

// ---------------------------------------------------------------------------
// Persistent fused kernel — round-4 structure (3 barriers/step, best measured:
// 875 us) with two strictly-additive tweaks:
//  * rec-GEMM kc=0 B-frags resident in registers (loaded once per layer)
//  * 1-op hsp unpack (p01<<16 / p01&0xffff0000)
// All code inline in the kernel body (round-6 lesson: helper-fn array params
// spill to scratch).
// ---------------------------------------------------------------------------
__global__ __launch_bounds__(NTHR, 4) void liquid_fused(KP P) {
  extern __shared__ char smem[];
  ushort* hb = (ushort*)smem;                            // [BROWS][LDA] bf16 LN'd h
  float2* stats = (float2*)(smem + BROWS * LDA * 2);     // [BROWS][STLD] per-wave (sum,sumsq)
  float2* stats2 = stats + BROWS * STLD;                 // [BROWS]       (-mu*rsig, rsig)

  const int tid = threadIdx.x;
  const int wv = tid >> 6;
  const int lane = tid & 63;
  const int q = lane >> 4;
  const int n = lane & 15;
  const int row0 = blockIdx.x * BROWS;
  const int wc0 = wv * 64;

  // ---- stage x tile (32 x 256 f32 -> bf16 in hb) for layer-0 input GEMM
  {
    const float4* x4 = (const float4*)P.x;
#pragma unroll
    for (int i = 0; i < 4; ++i) {
      int fi = i * NTHR + tid;           // 0..2047
      int r = fi >> 6;
      int c4 = fi & 63;
      float4 v = x4[(size_t)(row0 + r) * 64 + c4];
      uint2 o;
      o.x = cvt_pk_bf16(v.x, v.y);
      o.y = cvt_pk_bf16(v.z, v.w);
      *(uint2*)(hb + r * LDA + c4 * 4) = o;
    }
  }
  __syncthreads();

  v4f acc[2][4];          // GEMM accum / h_new scratch (C-layout)
  v4f base[2][4];         // scaled i_input + scaled bias, const over the 10 steps
  unsigned hsp[2][4][2];  // LN'd h state, packed bf16 pairs (matches LDS copy)
  float ac[4], c1[4], gc[4], bc[4];   // per-col params (dt*A, 1+dt/tau, g, b)

#pragma unroll 1
  for (int l = 0; l < 3; ++l) {
    const LayerP& L = P.L[l];
    float blx[4];
#pragma unroll
    for (int ct = 0; ct < 4; ++ct) {
      int col = wc0 + ct * 16 + n;
      ac[ct] = DT * L.Aamp[col];
      c1[ct] = 1.0f + DT / L.tau[col];
      gc[ct] = L.g[col];
      bc[ct] = L.b[col];
      blx[ct] = NLOG2E * L.bias[col];
    }

    // ---- resident kc=0 B-frags of W_rec for this layer (loop-invariant over
    //      the 10 steps; issued early so they complete under the W_in GEMM)
    v8s pb0 = *(const v8s*)(L.wrec + ((size_t)(wv * 4 + 0) * 64 + lane) * 8);
    v8s pb1 = *(const v8s*)(L.wrec + ((size_t)(wv * 4 + 1) * 64 + lane) * 8);
    v8s pb2 = *(const v8s*)(L.wrec + ((size_t)(wv * 4 + 2) * 64 + lane) * 8);
    v8s pb3 = *(const v8s*)(L.wrec + ((size_t)(wv * 4 + 3) * 64 + lane) * 8);

    // ---- i_input = x_in @ W_in (x_in is hb; weights pre-scaled by -log2e)
    if (l == 0) gemm_tiles<8, 32, 4, 2, true>(hb, L.win, wv, lane, acc, acc);
    else        gemm_tiles<16, 32, 4, 2, true>(hb, L.win, wv, lane, acc, acc);
#pragma unroll
    for (int rt = 0; rt < 2; ++rt)
#pragma unroll
      for (int ct = 0; ct < 4; ++ct)
#pragma unroll
        for (int r = 0; r < 4; ++r)
          base[rt][ct][r] = acc[rt][ct][r] + blx[ct];

#pragma unroll 1
    for (int s = 0; s < NSTEPS; ++s) {
      if (s > 0) {
        // rec accumulated ON TOP of base (C-init = base); kc=0 B from regs
        gemm_tiles_pf<16, 32, 4, 2>(hb, L.wrec, wv, lane, acc, base,
                                    pb0, pb1, pb2, pb3);
      } else {
#pragma unroll
        for (int rt = 0; rt < 2; ++rt)
#pragma unroll
          for (int ct = 0; ct < 4; ++ct)
            acc[rt][ct] = base[rt][ct];
      }

      // ---- EW-a: t = 1+exp2(z);  h_new = (hold*t + dt*A)/(c1*t + dt)
      //      fused with per-row LN partial stats; cross-lane reduce via DPP.
#pragma unroll
      for (int rt = 0; rt < 2; ++rt) {
        float ps[4], p2[4];
#pragma unroll
        for (int r = 0; r < 4; ++r) { ps[r] = 0.f; p2[r] = 0.f; }
#pragma unroll
        for (int ct = 0; ct < 4; ++ct) {
          float t0 = 1.0f + fexp2(acc[rt][ct][0]);
          float t1 = 1.0f + fexp2(acc[rt][ct][1]);
          float t2 = 1.0f + fexp2(acc[rt][ct][2]);
          float t3 = 1.0f + fexp2(acc[rt][ct][3]);
          float hn0, hn1, hn2, hn3;
          if (s == 0) {
            hn0 = ac[ct] * __builtin_amdgcn_rcpf(fmaf(c1[ct], t0, DT));
            hn1 = ac[ct] * __builtin_amdgcn_rcpf(fmaf(c1[ct], t1, DT));
            hn2 = ac[ct] * __builtin_amdgcn_rcpf(fmaf(c1[ct], t2, DT));
            hn3 = ac[ct] * __builtin_amdgcn_rcpf(fmaf(c1[ct], t3, DT));
          } else {
            unsigned p01 = hsp[rt][ct][0], p23 = hsp[rt][ct][1];
            float h0 = ubf2f(p01 << 16);
            float h1 = ubf2f(p01 & 0xffff0000u);
            float h2 = ubf2f(p23 << 16);
            float h3 = ubf2f(p23 & 0xffff0000u);
            hn0 = fmaf(h0, t0, ac[ct]) * __builtin_amdgcn_rcpf(fmaf(c1[ct], t0, DT));
            hn1 = fmaf(h1, t1, ac[ct]) * __builtin_amdgcn_rcpf(fmaf(c1[ct], t1, DT));
            hn2 = fmaf(h2, t2, ac[ct]) * __builtin_amdgcn_rcpf(fmaf(c1[ct], t2, DT));
            hn3 = fmaf(h3, t3, ac[ct]) * __builtin_amdgcn_rcpf(fmaf(c1[ct], t3, DT));
          }
          acc[rt][ct][0] = hn0; acc[rt][ct][1] = hn1;
          acc[rt][ct][2] = hn2; acc[rt][ct][3] = hn3;
          ps[0] += hn0; p2[0] = fmaf(hn0, hn0, p2[0]);
          ps[1] += hn1; p2[1] = fmaf(hn1, hn1, p2[1]);
          ps[2] += hn2; p2[2] = fmaf(hn2, hn2, p2[2]);
          ps[3] += hn3; p2[3] = fmaf(hn3, hn3, p2[3]);
        }
#pragma unroll
        for (int r = 0; r < 4; ++r) { ps[r] = rowsum16(ps[r]); p2[r] = rowsum16(p2[r]); }
        if (n == 0) {
#pragma unroll
          for (int r = 0; r < 4; ++r)
            stats[(rt * 16 + q * 4 + r) * STLD + wv] = make_float2(ps[r], p2[r]);
        }
      }
      __syncthreads();   // bar P: partials visible; all hb GEMM reads done
      if (tid < BROWS) {
        float S = 0.f, S2 = 0.f;
#pragma unroll
        for (int i = 0; i < 8; ++i) {
          float2 t = stats[tid * STLD + i];
          S += t.x;
          S2 += t.y;
        }
        float mu = S * (1.0f / HDIM);
        float var = fmaf(-mu, mu, S2 * (1.0f / HDIM));
        float rs = __builtin_amdgcn_rsqf(var + LNEPS);
        stats2[tid] = make_float2(-mu * rs, rs);
      }
      __syncthreads();   // bar S

      // ---- EW-b: normalize (2 fma), update register h state, write bf16 h
#pragma unroll
      for (int rt = 0; rt < 2; ++rt) {
        float2 st[4];
#pragma unroll
        for (int r = 0; r < 4; ++r)
          st[r] = stats2[rt * 16 + q * 4 + r];
#pragma unroll
        for (int ct = 0; ct < 4; ++ct) {
          float v0 = fmaf(fmaf(acc[rt][ct][0], st[0].y, st[0].x), gc[ct], bc[ct]);
          float v1 = fmaf(fmaf(acc[rt][ct][1], st[1].y, st[1].x), gc[ct], bc[ct]);
          float v2 = fmaf(fmaf(acc[rt][ct][2], st[2].y, st[2].x), gc[ct], bc[ct]);
          float v3 = fmaf(fmaf(acc[rt][ct][3], st[3].y, st[3].x), gc[ct], bc[ct]);
          unsigned p01 = cvt_pk_bf16(v0, v1);
          unsigned p23 = cvt_pk_bf16(v2, v3);
          hsp[rt][ct][0] = p01;
          hsp[rt][ct][1] = p23;
          ushort* wp = hb + (rt * 16 + q * 4) * LDA + wc0 + ct * 16 + n;
          wp[0]       = (ushort)p01;
          wp[LDA]     = (ushort)(p01 >> 16);
          wp[2 * LDA] = (ushort)p23;
          wp[3 * LDA] = (ushort)(p23 >> 16);
        }
      }
      __syncthreads();   // bar H: LN'd h stable for next GEMM
    }
  }

  // ---- output projection: out = h @ out_W^T + out_b  (N=128, wave owns 16 cols)
  v4f oa[2];
#pragma unroll
  for (int rt = 0; rt < 2; ++rt) oa[rt] = (v4f){0.f, 0.f, 0.f, 0.f};
#pragma unroll
  for (int kc = 0; kc < 16; ++kc) {
    v8s b = *(const v8s*)(P.wout + ((size_t)(kc * 8 + wv) * 64 + lane) * 8);
#pragma unroll
    for (int rt = 0; rt < 2; ++rt) {
      v8s a = *(const v8s*)(hb + (rt * 16 + n) * LDA + kc * 32 + q * 8);
      oa[rt] = __builtin_amdgcn_mfma_f32_16x16x32_bf16(a, b, oa[rt], 0, 0, 0);
    }
  }
  {
    int col = wv * 16 + n;
    float ob = P.outb[col];
#pragma unroll
    for (int rt = 0; rt < 2; ++rt)
#pragma unroll
      for (int r = 0; r < 4; ++r)
        P.out[(size_t)(row0 + rt * 16 + q * 4 + r) * 128 + col] = oa[rt][r] + ob;
  }
}

// ---------------------------------------------------------------------------
extern "C" void kernel_launch(void* const* d_in, const int* in_sizes, int n_in,
                              void* d_out, int out_size, void* d_ws, size_t ws_size,
                              hipStream_t stream) {
  (void)in_sizes; (void)n_in; (void)out_size; (void)ws_size;
  ushort* ws = (ushort*)d_ws;

  // ws layout (bf16 elems), all 16B aligned
  const size_t S_WIN0 = 0;                                  //  8*32*64*8 = 131072
  const size_t S_WIN1 = S_WIN0 + (size_t)8 * 32 * 64 * 8;   // 16*32*64*8 = 262144 each below
  const size_t S_WIN2 = S_WIN1 + (size_t)16 * 32 * 64 * 8;
  const size_t S_REC0 = S_WIN2 + (size_t)16 * 32 * 64 * 8;
  const size_t S_REC1 = S_REC0 + (size_t)16 * 32 * 64 * 8;
  const size_t S_REC2 = S_REC1 + (size_t)16 * 32 * 64 * 8;
  const size_t S_WOUT = S_REC2 + (size_t)16 * 32 * 64 * 8;  // 16*8*64*8 = 65536

  const float* f[27];
  for (int i = 0; i < 27; ++i) f[i] = (const float*)d_in[i];

  dim3 bt(256);
  // W_in / W_rec / (bias, in-kernel) pre-scaled by -log2e; W_out raw.
  pack_w<<<dim3(64),  bt, 0, stream>>>(f[1],  nullptr, ws + S_WIN0, 256, 512, 0, NLOG2E);
  pack_w<<<dim3(128), bt, 0, stream>>>(f[9],  nullptr, ws + S_WIN1, 512, 512, 0, NLOG2E);
  pack_w<<<dim3(128), bt, 0, stream>>>(f[17], nullptr, ws + S_WIN2, 512, 512, 0, NLOG2E);
  pack_w<<<dim3(128), bt, 0, stream>>>(f[2],  f[6],    ws + S_REC0, 512, 512, 1, NLOG2E);
  pack_w<<<dim3(128), bt, 0, stream>>>(f[10], f[14],   ws + S_REC1, 512, 512, 1, NLOG2E);
  pack_w<<<dim3(128), bt, 0, stream>>>(f[18], f[22],   ws + S_REC2, 512, 512, 1, NLOG2E);
  pack_w<<<dim3(32),  bt, 0, stream>>>(f[25], nullptr, ws + S_WOUT, 512, 128, 1, 1.0f);

  KP P;
  P.x = f[0];
  const size_t win_off[3] = {S_WIN0, S_WIN1, S_WIN2};
  const size_t rec_off[3] = {S_REC0, S_REC1, S_REC2};
  for (int l = 0; l < 3; ++l) {
    int bi = 1 + 8 * l;
    P.L[l].win = ws + win_off[l];
    P.L[l].wrec = ws + rec_off[l];
    P.L[l].bias = f[bi + 2];
    P.L[l].tau = f[bi + 3];
    P.L[l].Aamp = f[bi + 4];
    P.L[l].g = f[bi + 6];
    P.L[l].b = f[bi + 7];
  }
  P.wout = ws + S_WOUT;
  P.outb = f[26];
  P.out = (float*)d_out;

  const int smem = BROWS * LDA * 2 + BROWS * STLD * 8 + BROWS * 8;  // 35840 B
  hipFuncSetAttribute((const void*)liquid_fused,
                      hipFuncAttributeMaxDynamicSharedMemorySize, smem);
  liquid_fused<<<dim3(32768 / BROWS), dim3(NTHR), smem, stream>>>(P);
}

// Round 11
// 877.401 us; speedup vs baseline: 2.3949x; 2.3949x over previous
//
#include <hip/hip_runtime.h>

#define HDIM   512
#define BROWS  32
#define NTHR   512      // 8 waves; wave wv owns cols [64*wv, 64*wv+64) of H=512
#define LDA    520      // ushort elems per LDS row: 512 + 8 pad (breaks bank aliasing)
#define STLD   9        // float2 per stats row (8 waves + 1 pad)
#define NSTEPS 10
#define DT     0.1f
#define LNEPS  1e-5f
#define NLOG2E -1.4426950408889634f   // W_in/W_rec/bias pre-scaled: exp(-arg) == exp2(acc)

typedef __attribute__((ext_vector_type(8))) short v8s;   // 8 bf16 (4 VGPRs) MFMA operand
typedef __attribute__((ext_vector_type(4))) float v4f;   // 4 fp32 MFMA accum

static __device__ __forceinline__ ushort f2bf(float f) {
  union { float f; unsigned u; } v; v.f = f;
  unsigned r = v.u + 0x7fffu + ((v.u >> 16) & 1u);   // RNE
  return (ushort)(r >> 16);
}
static __device__ __forceinline__ float bf2f(unsigned hw) {
  union { unsigned u; float f; } v; v.u = hw << 16;
  return v.f;
}
// packed RNE bf16 pair: lo -> [15:0], hi -> [31:16] (bit-exact vs f2bf)
static __device__ __forceinline__ unsigned cvt_pk_bf16(float lo, float hi) {
  unsigned r;
  asm("v_cvt_pk_bf16_f32 %0, %1, %2" : "=v"(r) : "v"(lo), "v"(hi));
  return r;
}
static __device__ __forceinline__ float fexp2(float x) {
#if __has_builtin(__builtin_amdgcn_exp2f)
  return __builtin_amdgcn_exp2f(x);
#else
  float r; asm("v_exp_f32 %0, %1" : "=v"(r) : "v"(x)); return r;
#endif
}
// sum over the 16 lanes of each DPP row (lanes sharing q); result in every lane.
// VALU-only (keeps the LDS pipe free for GEMM A-frag reads).
static __device__ __forceinline__ float rowsum16(float x) {
  union { float f; int i; } u, v;
  u.f = x;
  v.i = __builtin_amdgcn_update_dpp(0, u.i, 0x121, 0xf, 0xf, false); u.f += v.f; // ror:1
  v.i = __builtin_amdgcn_update_dpp(0, u.i, 0x122, 0xf, 0xf, false); u.f += v.f; // ror:2
  v.i = __builtin_amdgcn_update_dpp(0, u.i, 0x124, 0xf, 0xf, false); u.f += v.f; // ror:4
  v.i = __builtin_amdgcn_update_dpp(0, u.i, 0x128, 0xf, 0xf, false); u.f += v.f; // ror:8
  return u.f;
}

// ---------------------------------------------------------------------------
// Pack a weight matrix into MFMA B-fragment order, bf16 (x scale):
//   B[k][n] with k = kc*32 + (lane>>4)*8 + j, n = ctg*16 + (lane&15)
//   dst frag index f = (kc*NT + ctg)*64 + lane, 8 bf16 each (16B, coalesced).
// trans==0: B[k][n] = src[k*N + n]          (W_in: x @ W)
// trans==1: B[k][n] = src[n*K + k] (*mask)  (W_rec^T masked, out_W^T)
// ---------------------------------------------------------------------------
__global__ void pack_w(const float* __restrict__ src, const float* __restrict__ msk,
                       ushort* __restrict__ dst, int K, int N, int trans, float scale) {
  int nt = N >> 4;
  int tot = (K >> 5) * nt * 64;
  int f = blockIdx.x * blockDim.x + threadIdx.x;
  if (f >= tot) return;
  int flane = f & 63;
  int rest = f >> 6;
  int ctg = rest % nt;
  int kc = rest / nt;
  int n = ctg * 16 + (flane & 15);
  int kb = kc * 32 + ((flane >> 4) & 3) * 8;
  ushort v[8];
#pragma unroll
  for (int j = 0; j < 8; ++j) {
    int k = kb + j;
    float s;
    if (trans) {
      s = src[(size_t)n * K + k];
      if (msk) s *= msk[(size_t)n * K + k];
    } else {
      s = src[(size_t)k * N + n];
    }
    v[j] = f2bf(s * scale);
  }
  uint4 u;
  u.x = (unsigned)v[0] | ((unsigned)v[1] << 16);
  u.y = (unsigned)v[2] | ((unsigned)v[3] << 16);
  u.z = (unsigned)v[4] | ((unsigned)v[5] << 16);
  u.w = (unsigned)v[6] | ((unsigned)v[7] << 16);
  *(uint4*)(dst + (size_t)f * 8) = u;
}

// ---------------------------------------------------------------------------
// GEMM: acc[rt][ct] = (ZI ? 0 : init[rt][ct]) + hb(16*RT x 32*KC) @ W(32*KC x 16*NT)
// C-init with `base` kills the per-step "+base" adds in the elementwise phase.
// A-frag: A[m=lane&15][k=(lane>>4)*8+j]  -> contiguous ds_read_b128.
// B-frag: packed global, one 16B load per tile (coalesced, L2-resident).
// C/D: row = (lane>>4)*4 + reg, col = lane&15 (within 16x16 tile).
// ---------------------------------------------------------------------------
template <int KC, int NT, int NCT, int RT, bool ZI>
static __device__ __forceinline__ void gemm_tiles(const ushort* hb, const ushort* __restrict__ w,
                                                  int wv, int lane, v4f acc[RT][NCT],
                                                  const v4f init[RT][NCT]) {
  const int q = lane >> 4, n = lane & 15;
#pragma unroll
  for (int rt = 0; rt < RT; ++rt)
#pragma unroll
    for (int ct = 0; ct < NCT; ++ct)
      acc[rt][ct] = ZI ? (v4f){0.f, 0.f, 0.f, 0.f} : init[rt][ct];
#pragma unroll
  for (int kc = 0; kc < KC; ++kc) {
    v8s a[RT];
#pragma unroll
    for (int rt = 0; rt < RT; ++rt)
      a[rt] = *(const v8s*)(hb + (rt * 16 + n) * LDA + kc * 32 + q * 8);
#pragma unroll
    for (int ct = 0; ct < NCT; ++ct) {
      const int ctg = wv * NCT + ct;
      v8s b = *(const v8s*)(w + ((size_t)(kc * NT + ctg) * 64 + lane) * 8);
#pragma unroll
      for (int rt = 0; rt < RT; ++rt)
        acc[rt][ct] = __builtin_amdgcn_mfma_f32_16x16x32_bf16(a[rt], b, acc[rt][ct], 0, 0, 0);
    }
  }
}

struct LayerP {
  const ushort* win;
  const ushort* wrec;
  const float* bias;
  const float* tau;
  const float* Aamp;
  const float* g;
  const float* b;
};
struct KP {
  const float* x;
  LayerP L[3];
  const ushort* wout;
  const float* outb;
  float* out;
};

// ---------------------------------------------------------------------------
// Persistent fused kernel: each block owns 32 batch rows through
// 3 layers x 10 ODE steps + LayerNorm + output projection.
// 512 threads = 8 waves; wave wv owns cols [64*wv, 64*wv+64) of H=512.
// Geometry = round-1's verified spill-free shape (2 blocks/CU, cross-block
// barrier overlap). VALU cuts (round 4, best measured = 875 us):
//   * weights/bias in exp2 domain -> t = 1+exp2(z), 1 transcendental saved
//   * rec-GEMM C-init = base      -> no "+base" add per element
//   * stats2 = (-mu*rsig, rsig)   -> normalize = 2 fma
// Per-thread persistents: acc 32 + base 32 + hsp 16 + params 16 = 96 regs —
// the 128-reg/4-wave bucket is FULL: any persistent addition spills (R6/R10:
// 2.3x regression). Structural neighbors all measured worse (R3,R5-R10).
// ---------------------------------------------------------------------------
__global__ __launch_bounds__(NTHR, 4) void liquid_fused(KP P) {
  extern __shared__ char smem[];
  ushort* hb = (ushort*)smem;                            // [BROWS][LDA] bf16 LN'd h
  float2* stats = (float2*)(smem + BROWS * LDA * 2);     // [BROWS][STLD] per-wave (sum,sumsq)
  float2* stats2 = stats + BROWS * STLD;                 // [BROWS]       (-mu*rsig, rsig)

  const int tid = threadIdx.x;
  const int wv = tid >> 6;
  const int lane = tid & 63;
  const int q = lane >> 4;
  const int n = lane & 15;
  const int row0 = blockIdx.x * BROWS;
  const int wc0 = wv * 64;

  // ---- stage x tile (32 x 256 f32 -> bf16 in hb) for layer-0 input GEMM
  {
    const float4* x4 = (const float4*)P.x;
#pragma unroll
    for (int i = 0; i < 4; ++i) {
      int fi = i * NTHR + tid;           // 0..2047
      int r = fi >> 6;
      int c4 = fi & 63;
      float4 v = x4[(size_t)(row0 + r) * 64 + c4];
      uint2 o;
      o.x = cvt_pk_bf16(v.x, v.y);
      o.y = cvt_pk_bf16(v.z, v.w);
      *(uint2*)(hb + r * LDA + c4 * 4) = o;
    }
  }
  __syncthreads();

  v4f acc[2][4];          // GEMM accum / h_new scratch (C-layout)
  v4f base[2][4];         // scaled i_input + scaled bias, const over the 10 steps
  unsigned hsp[2][4][2];  // LN'd h state, packed bf16 pairs (matches LDS copy)
  float ac[4], c1[4], gc[4], bc[4];   // per-col params (dt*A, 1+dt/tau, g, b)

#pragma unroll 1
  for (int l = 0; l < 3; ++l) {
    const LayerP& L = P.L[l];
    float blx[4];
#pragma unroll
    for (int ct = 0; ct < 4; ++ct) {
      int col = wc0 + ct * 16 + n;
      ac[ct] = DT * L.Aamp[col];
      c1[ct] = 1.0f + DT / L.tau[col];
      gc[ct] = L.g[col];
      bc[ct] = L.b[col];
      blx[ct] = NLOG2E * L.bias[col];
    }

    // ---- i_input = x_in @ W_in (x_in is hb; weights pre-scaled by -log2e)
    if (l == 0) gemm_tiles<8, 32, 4, 2, true>(hb, L.win, wv, lane, acc, acc);
    else        gemm_tiles<16, 32, 4, 2, true>(hb, L.win, wv, lane, acc, acc);
#pragma unroll
    for (int rt = 0; rt < 2; ++rt)
#pragma unroll
      for (int ct = 0; ct < 4; ++ct)
#pragma unroll
        for (int r = 0; r < 4; ++r)
          base[rt][ct][r] = acc[rt][ct][r] + blx[ct];

#pragma unroll 1
    for (int s = 0; s < NSTEPS; ++s) {
      if (s > 0) {
        // rec accumulated ON TOP of base (C-init = base)
        gemm_tiles<16, 32, 4, 2, false>(hb, L.wrec, wv, lane, acc, base);
      } else {
#pragma unroll
        for (int rt = 0; rt < 2; ++rt)
#pragma unroll
          for (int ct = 0; ct < 4; ++ct)
            acc[rt][ct] = base[rt][ct];
      }

      // ---- t = 1+exp2(z) (= 1+exp(-arg));  h_new = (h*t + dt*A)/(c1*t + dt)
      //      fused with per-row LN partial stats; cross-lane reduce via DPP.
#pragma unroll
      for (int rt = 0; rt < 2; ++rt) {
        float ps[4], p2[4];
#pragma unroll
        for (int r = 0; r < 4; ++r) { ps[r] = 0.f; p2[r] = 0.f; }
#pragma unroll
        for (int ct = 0; ct < 4; ++ct)
#pragma unroll
          for (int r = 0; r < 4; ++r) {
            float t = 1.0f + fexp2(acc[rt][ct][r]);
            float hold = (s == 0) ? 0.0f
                                  : bf2f((hsp[rt][ct][r >> 1] >> ((r & 1) * 16)) & 0xffffu);
            float hn = fmaf(hold, t, ac[ct]) *
                       __builtin_amdgcn_rcpf(fmaf(c1[ct], t, DT));
            acc[rt][ct][r] = hn;
            ps[r] += hn;
            p2[r] = fmaf(hn, hn, p2[r]);
          }
#pragma unroll
        for (int r = 0; r < 4; ++r) { ps[r] = rowsum16(ps[r]); p2[r] = rowsum16(p2[r]); }
        if (n == 0) {
#pragma unroll
          for (int r = 0; r < 4; ++r)
            stats[(rt * 16 + q * 4 + r) * STLD + wv] = make_float2(ps[r], p2[r]);
        }
      }
      __syncthreads();
      if (tid < BROWS) {
        float S = 0.f, S2 = 0.f;
#pragma unroll
        for (int i = 0; i < 8; ++i) {
          float2 t = stats[tid * STLD + i];
          S += t.x;
          S2 += t.y;
        }
        float mu = S * (1.0f / HDIM);
        float var = fmaf(-mu, mu, S2 * (1.0f / HDIM));
        float rsig = __builtin_amdgcn_rsqf(var + LNEPS);
        stats2[tid] = make_float2(-mu * rsig, rsig);
      }
      __syncthreads();

      // ---- normalize (2 fma), update register h state, write bf16 h to LDS
#pragma unroll
      for (int rt = 0; rt < 2; ++rt) {
        float2 st[4];
#pragma unroll
        for (int r = 0; r < 4; ++r)
          st[r] = stats2[rt * 16 + q * 4 + r];
#pragma unroll
        for (int ct = 0; ct < 4; ++ct) {
          float v0 = fmaf(fmaf(acc[rt][ct][0], st[0].y, st[0].x), gc[ct], bc[ct]);
          float v1 = fmaf(fmaf(acc[rt][ct][1], st[1].y, st[1].x), gc[ct], bc[ct]);
          float v2 = fmaf(fmaf(acc[rt][ct][2], st[2].y, st[2].x), gc[ct], bc[ct]);
          float v3 = fmaf(fmaf(acc[rt][ct][3], st[3].y, st[3].x), gc[ct], bc[ct]);
          unsigned p01 = cvt_pk_bf16(v0, v1);
          unsigned p23 = cvt_pk_bf16(v2, v3);
          hsp[rt][ct][0] = p01;
          hsp[rt][ct][1] = p23;
          ushort* wp = hb + (rt * 16 + q * 4) * LDA + wc0 + ct * 16 + n;
          wp[0]       = (ushort)p01;
          wp[LDA]     = (ushort)(p01 >> 16);
          wp[2 * LDA] = (ushort)p23;
          wp[3 * LDA] = (ushort)(p23 >> 16);
        }
      }
      __syncthreads();
    }
  }

  // ---- output projection: out = h @ out_W^T + out_b  (N=128, wave owns 16 cols)
  v4f oa[2];
#pragma unroll
  for (int rt = 0; rt < 2; ++rt) oa[rt] = (v4f){0.f, 0.f, 0.f, 0.f};
#pragma unroll
  for (int kc = 0; kc < 16; ++kc) {
    v8s b = *(const v8s*)(P.wout + ((size_t)(kc * 8 + wv) * 64 + lane) * 8);
#pragma unroll
    for (int rt = 0; rt < 2; ++rt) {
      v8s a = *(const v8s*)(hb + (rt * 16 + n) * LDA + kc * 32 + q * 8);
      oa[rt] = __builtin_amdgcn_mfma_f32_16x16x32_bf16(a, b, oa[rt], 0, 0, 0);
    }
  }
  {
    int col = wv * 16 + n;
    float ob = P.outb[col];
#pragma unroll
    for (int rt = 0; rt < 2; ++rt)
#pragma unroll
      for (int r = 0; r < 4; ++r)
        P.out[(size_t)(row0 + rt * 16 + q * 4 + r) * 128 + col] = oa[rt][r] + ob;
  }
}

// ---------------------------------------------------------------------------
extern "C" void kernel_launch(void* const* d_in, const int* in_sizes, int n_in,
                              void* d_out, int out_size, void* d_ws, size_t ws_size,
                              hipStream_t stream) {
  (void)in_sizes; (void)n_in; (void)out_size; (void)ws_size;
  ushort* ws = (ushort*)d_ws;

  // ws layout (bf16 elems), all 16B aligned
  const size_t S_WIN0 = 0;                                  //  8*32*64*8 = 131072
  const size_t S_WIN1 = S_WIN0 + (size_t)8 * 32 * 64 * 8;   // 16*32*64*8 = 262144 each below
  const size_t S_WIN2 = S_WIN1 + (size_t)16 * 32 * 64 * 8;
  const size_t S_REC0 = S_WIN2 + (size_t)16 * 32 * 64 * 8;
  const size_t S_REC1 = S_REC0 + (size_t)16 * 32 * 64 * 8;
  const size_t S_REC2 = S_REC1 + (size_t)16 * 32 * 64 * 8;
  const size_t S_WOUT = S_REC2 + (size_t)16 * 32 * 64 * 8;  // 16*8*64*8 = 65536

  const float* f[27];
  for (int i = 0; i < 27; ++i) f[i] = (const float*)d_in[i];

  dim3 bt(256);
  // W_in / W_rec / (bias, in-kernel) pre-scaled by -log2e; W_out raw.
  pack_w<<<dim3(64),  bt, 0, stream>>>(f[1],  nullptr, ws + S_WIN0, 256, 512, 0, NLOG2E);
  pack_w<<<dim3(128), bt, 0, stream>>>(f[9],  nullptr, ws + S_WIN1, 512, 512, 0, NLOG2E);
  pack_w<<<dim3(128), bt, 0, stream>>>(f[17], nullptr, ws + S_WIN2, 512, 512, 0, NLOG2E);
  pack_w<<<dim3(128), bt, 0, stream>>>(f[2],  f[6],    ws + S_REC0, 512, 512, 1, NLOG2E);
  pack_w<<<dim3(128), bt, 0, stream>>>(f[10], f[14],   ws + S_REC1, 512, 512, 1, NLOG2E);
  pack_w<<<dim3(128), bt, 0, stream>>>(f[18], f[22],   ws + S_REC2, 512, 512, 1, NLOG2E);
  pack_w<<<dim3(32),  bt, 0, stream>>>(f[25], nullptr, ws + S_WOUT, 512, 128, 1, 1.0f);

  KP P;
  P.x = f[0];
  const size_t win_off[3] = {S_WIN0, S_WIN1, S_WIN2};
  const size_t rec_off[3] = {S_REC0, S_REC1, S_REC2};
  for (int l = 0; l < 3; ++l) {
    int bi = 1 + 8 * l;
    P.L[l].win = ws + win_off[l];
    P.L[l].wrec = ws + rec_off[l];
    P.L[l].bias = f[bi + 2];
    P.L[l].tau = f[bi + 3];
    P.L[l].Aamp = f[bi + 4];
    P.L[l].g = f[bi + 6];
    P.L[l].b = f[bi + 7];
  }
  P.wout = ws + S_WOUT;
  P.outb = f[26];
  P.out = (float*)d_out;

  const int smem = BROWS * LDA * 2 + BROWS * STLD * 8 + BROWS * 8;  // 35840 B
  hipFuncSetAttribute((const void*)liquid_fused,
                      hipFuncAttributeMaxDynamicSharedMemorySize, smem);
  liquid_fused<<<dim3(32768 / BROWS), dim3(NTHR), smem, stream>>>(P);
}